// Round 8
// baseline (81.002 us; speedup 1.0000x reference)
//
#include <hip/hip_runtime.h>

#define BB 8
#define TT 2048
#define DD 128
#define CH 16              // 128-row k-chunks; gram grid = CH*BB = 128 blocks

typedef __attribute__((ext_vector_type(8))) short bf16x8;
typedef __attribute__((ext_vector_type(4))) float f32x4;
typedef unsigned short u16;

static __device__ __forceinline__ float bf2f(u16 u) {
    union { unsigned int i; float f; } v; v.i = ((unsigned int)u) << 16; return v.f;
}
static __device__ __forceinline__ u16 f2bf(float f) {
    union { float f; unsigned int i; } v; v.f = f;
    unsigned int x = v.i;
    return (u16)((x + 0x7FFFu + ((x >> 16) & 1u)) >> 16);  // RNE
}

// ===========================================================================
// R8: TWO kernels (dispatch overhead ~6us each is the largest controllable
// term; fill ~44us is harness-fixed). K2 absorbs the reduce: P[*][b] is
// XCD-local in L2 (b = bid&7 on both kernels), so the 512KB/block re-read
// costs ~3.7us GPU-wide, cheaper than the kernel boundary it replaces.
//
// K1 = R7 gram (verified: swizzled staging, 0 bank conflicts) extended to
//      128-row chunks via two 64-row sub-phases, double-buffered LDS,
//      register prefetch. P layout/numerics = R0 baseline (CH=16).
// K2 = elementwise P-reduce straight into frag-keyed Gs (LDS), then the
//      R7-verified MFMA apply + epilogue.
// ===========================================================================

// ---------------------------------------------------------------------------
// K1: P[c][b] = enc[b][c*128 .. +127]^T @ (same), K=128, fp32 MFMA accum.
// P frag-keyed: elem (row,col) of tile (i,j) at (i*8+j)*256 + col*16 + row.
// ---------------------------------------------------------------------------
__global__ __launch_bounds__(1024, 4) void gram_mfma(const float* __restrict__ enc,
                                                     u16* __restrict__ P) {
    const int bid  = blockIdx.x;           // 0..127
    const int b    = bid & 7;              // XCD-local batch
    const int c    = bid >> 3;             // k-chunk 0..15 (128 rows)
    const int t    = threadIdx.x;
    const int wave = t >> 6, lane = t & 63, quad = lane >> 4, ln = lane & 15;

    __shared__ __align__(16) u16 Gt[2][DD * 64];   // 2 x 16 KB swizzled enc^T

    const int d = t & 127, kg = t >> 7;    // column d, k-granule kg (8 k's)
    const float* src = enc + ((size_t)b * TT + (size_t)c * 128) * DD;

    // Prefetch sub-phase 0 (rows 0..63 of the chunk).
    float pf[8];
    #pragma unroll
    for (int i = 0; i < 8; ++i) pf[i] = src[(kg * 8 + i) * DD + d];

    const int mt = wave >> 1, parity = wave & 1;
    f32x4 acc[4];
    #pragma unroll
    for (int s = 0; s < 4; ++s) acc[s] = (f32x4){0.f, 0.f, 0.f, 0.f};

    #pragma unroll
    for (int tt = 0; tt < 2; ++tt) {
        // Convert prefetched values, write one swizzled 16B granule.
        {
            union { u16 o[8]; uint4 q; } cv;
            #pragma unroll
            for (int i = 0; i < 8; ++i) cv.o[i] = f2bf(pf[i]);
            *(uint4*)&Gt[tt][d * 64 + ((kg ^ (d & 7)) << 3)] = cv.q;
        }
        // Prefetch sub-phase 1 (rows 64..127) while phase 0 syncs/computes.
        if (tt == 0) {
            #pragma unroll
            for (int i = 0; i < 8; ++i) pf[i] = src[(64 + kg * 8 + i) * DD + d];
        }
        __syncthreads();   // buf tt staged (writes to buf tt^1 next iter are disjoint)

        #pragma unroll
        for (int ks = 0; ks < 2; ++ks) {
            const int g = ((ks * 4 + quad) ^ (ln & 7)) << 3;   // swizzled granule
            const bf16x8 af = *(const bf16x8*)&Gt[tt][(mt * 16 + ln) * 64 + g];
            #pragma unroll
            for (int s = 0; s < 4; ++s) {
                const int nt = parity + 2 * s;
                const bf16x8 bf = *(const bf16x8*)&Gt[tt][(nt * 16 + ln) * 64 + g];
                acc[s] = __builtin_amdgcn_mfma_f32_16x16x32_bf16(af, bf, acc[s], 0, 0, 0);
            }
        }
    }

    // P write (R7 verbatim): frag-keyed, ushort4 per tile-slot.
    u16* Pb = P + ((size_t)c * BB + b) * (DD * DD);
    #pragma unroll
    for (int s = 0; s < 4; ++s) {
        const int nt = parity + 2 * s;
        u16 o[4];
        #pragma unroll
        for (int r = 0; r < 4; ++r) o[r] = f2bf(acc[s][r]);
        *(ushort4*)&Pb[(mt * 8 + nt) * 256 + ln * 16 + quad * 4] = *(const ushort4*)o;
    }
}

// ---------------------------------------------------------------------------
// K2: Gs = sum_c P[c][b] (elementwise, fp32 accum, frag-keyed in LDS), then
// out[b,q-chunk] = dec_chunk @ Gs (R7-verified MFMA apply + epilogue).
// ---------------------------------------------------------------------------
__global__ __launch_bounds__(1024, 4) void reduce_apply(const float* __restrict__ dec,
                                                        const u16* __restrict__ P,
                                                        float* __restrict__ out) {
    const int bid  = blockIdx.x;           // 0..255
    const int b    = bid & 7;              // same XCD as K1's batch-b blocks
    const int q    = bid >> 3;             // q-chunk 0..31
    const int t    = threadIdx.x;
    const int wave = t >> 6, lane = t & 63, quad = lane >> 4, ln = lane & 15;

    __shared__ __align__(16) u16 Gs[DD * DD];     // 32 KB frag-keyed G

    // dec loads first (HBM latency hides under the P-reduce) -> A-frags.
    const int rowt = wave & 3, dgrp = wave >> 2;
    const float* drow = dec + ((size_t)b * TT + (size_t)q * 64 + rowt * 16 + ln) * DD
                        + quad * 8;
    bf16x8 dfrag[4];
    #pragma unroll
    for (int ks = 0; ks < 4; ++ks) {
        const float4 d0 = *(const float4*)(drow + ks * 32);
        const float4 d1 = *(const float4*)(drow + ks * 32 + 4);
        union { u16 o[8]; bf16x8 v; } u;
        u.o[0] = f2bf(d0.x); u.o[1] = f2bf(d0.y); u.o[2] = f2bf(d0.z); u.o[3] = f2bf(d0.w);
        u.o[4] = f2bf(d1.x); u.o[5] = f2bf(d1.y); u.o[6] = f2bf(d1.z); u.o[7] = f2bf(d1.w);
        dfrag[ks] = u.v;
    }

    // Reduce P[*][b] -> Gs: each thread owns 2 uint4 (16 u16) of G.
    // Element-wise in the frag-keyed index space, XCD-local L2 reads.
    #pragma unroll
    for (int i = 0; i < 2; ++i) {
        const int g = i * 1024 + t;        // uint4 index 0..2047
        const uint4* Pu = (const uint4*)P;
        float s[8];
        #pragma unroll
        for (int j = 0; j < 8; ++j) s[j] = 0.f;
        #pragma unroll
        for (int c2 = 0; c2 < CH; ++c2) {
            const uint4 v = Pu[((size_t)c2 * BB + b) * 2048 + g];
            s[0] += bf2f((u16)(v.x & 0xffff)); s[1] += bf2f((u16)(v.x >> 16));
            s[2] += bf2f((u16)(v.y & 0xffff)); s[3] += bf2f((u16)(v.y >> 16));
            s[4] += bf2f((u16)(v.z & 0xffff)); s[5] += bf2f((u16)(v.z >> 16));
            s[6] += bf2f((u16)(v.w & 0xffff)); s[7] += bf2f((u16)(v.w >> 16));
        }
        union { u16 o[8]; uint4 qv; } cv;
        #pragma unroll
        for (int j = 0; j < 8; ++j) cv.o[j] = f2bf(s[j]);
        ((uint4*)Gs)[g] = cv.qv;
    }
    __syncthreads();

    // MFMA apply (R7 verbatim): wave (rowt, dgrp) = 16 dec rows x 32 out cols.
    f32x4 oacc[2];
    #pragma unroll
    for (int dtl = 0; dtl < 2; ++dtl) oacc[dtl] = (f32x4){0.f, 0.f, 0.f, 0.f};

    #pragma unroll
    for (int ks = 0; ks < 4; ++ks) {
        const int mtk  = ks * 2 + (quad >> 1);
        const int boff = ln * 16 + (quad & 1) * 8;
        #pragma unroll
        for (int dtl = 0; dtl < 2; ++dtl) {
            const int dt = dgrp * 2 + dtl;
            const bf16x8 bbf = *(const bf16x8*)&Gs[(mtk * 8 + dt) * 256 + boff];
            oacc[dtl] = __builtin_amdgcn_mfma_f32_16x16x32_bf16(
                dfrag[ks], bbf, oacc[dtl], 0, 0, 0);
        }
    }

    // Epilogue: C/D layout col=lane&15, row=quad*4+reg (HW-verified).
    float* ob = out + ((size_t)b * TT + (size_t)q * 64 + rowt * 16) * DD;
    #pragma unroll
    for (int dtl = 0; dtl < 2; ++dtl) {
        const int dcol = (dgrp * 2 + dtl) * 16 + ln;
        #pragma unroll
        for (int r = 0; r < 4; ++r)
            ob[(quad * 4 + r) * DD + dcol] = oacc[dtl][r];
    }
}

extern "C" void kernel_launch(void* const* d_in, const int* in_sizes, int n_in,
                              void* d_out, int out_size, void* d_ws, size_t ws_size,
                              hipStream_t stream) {
    const float* enc = (const float*)d_in[0];  // (8,2048,128) fp32
    const float* dec = (const float*)d_in[1];  // (8,2048,128) fp32
    float* out = (float*)d_out;                // (8,2048,128) fp32

    // ws: P bf16 partials (CH*BB*128*128*2 = 4 MB)
    u16* P = (u16*)d_ws;

    gram_mfma<<<dim3(CH * BB), 1024, 0, stream>>>(enc, P);
    reduce_apply<<<dim3(32 * BB), 1024, 0, stream>>>(dec, P, out);
}